// Round 12
// baseline (233.623 us; speedup 1.0000x reference)
//
#include <hip/hip_runtime.h>
#include <hip/hip_bf16.h>
#include <math.h>

using bf16 = __hip_bfloat16;
typedef __bf16 bf16x8v __attribute__((ext_vector_type(8)));
typedef float f32x4v __attribute__((ext_vector_type(4)));

#define AS1 __attribute__((address_space(1)))
#define AS3 __attribute__((address_space(3)))

// async global->LDS, 16B/lane; LDS dest = wave-uniform base + lane*16
__device__ __forceinline__ void g2l16(const void* g, void* l) {
  __builtin_amdgcn_global_load_lds((const AS1 void*)g, (AS3 void*)l, 16, 0, 0);
}

__device__ __forceinline__ float fclamp(float v) {
  return fminf(fmaxf(v, -6.0e4f), 6.0e4f);  // NaN firewall
}

// pack two floats to adjacent bf16 (compiler emits v_cvt_pk_bf16_f32)
__device__ __forceinline__ unsigned packbf(float a, float b) {
  unsigned short lo = __builtin_bit_cast(unsigned short, __float2bfloat16(a));
  unsigned short hi = __builtin_bit_cast(unsigned short, __float2bfloat16(b));
  return (unsigned)lo | ((unsigned)hi << 16);
}

// scale*log2(e), folded into Q projection so attn uses plain exp2
#define QSCL 0.1803368801111204f

// ---------------------------------------------------------------------------
// Merged prep: activations fp32->bf16 (lin < 6144) + weight transpose+cvt
// (lin >= 6144).
// ---------------------------------------------------------------------------
__global__ __launch_bounds__(256) void prep(
    const float* __restrict__ q, const float* __restrict__ k,
    const float* __restrict__ v,
    const float* __restrict__ w0, const float* __restrict__ w1,
    const float* __restrict__ w2, const float* __restrict__ w3,
    bf16* __restrict__ oq, bf16* __restrict__ ok, bf16* __restrict__ ov,
    bf16* __restrict__ o0, bf16* __restrict__ o1,
    bf16* __restrict__ o2, bf16* __restrict__ o3) {
  __shared__ alignas(16) bf16 tile[64][80];
  const int t = threadIdx.x;
  const int lin = blockIdx.x;
  if (lin < 6144) {  // cvt path: 3 tensors x 2048 blocks
    const int tensor = lin >> 11, blk = lin & 2047;
    const float* in = (tensor == 0) ? q : (tensor == 1) ? k : v;
    bf16* out = (tensor == 0) ? oq : (tensor == 1) ? ok : ov;
    int i = (blk * 256 + t) * 8;
    float4 a = *(const float4*)&in[i];
    float4 b = *(const float4*)&in[i + 4];
    uint4 u;
    u.x = packbf(a.x, a.y); u.y = packbf(a.z, a.w);
    u.z = packbf(b.x, b.y); u.w = packbf(b.z, b.w);
    *(uint4*)&out[i] = u;
    return;
  }
  // transpose path: 4 weights x 256 tiles
  const int rem = lin - 6144;
  const int z = rem >> 8, xy = rem & 255;
  const float* in = (z == 0) ? w0 : (z == 1) ? w1 : (z == 2) ? w2 : w3;
  bf16* out = (z == 0) ? o0 : (z == 1) ? o1 : (z == 2) ? o2 : o3;
  const int bx = (xy & 15) * 64, by = (xy >> 4) * 64;
#pragma unroll
  for (int p = 0; p < 4; ++p) {
    int idx = p * 1024 + t * 4;
    int r = idx >> 6, c0 = idx & 63;
    float4 vv = *(const float4*)&in[(size_t)(by + r) * 1024 + bx + c0];
    tile[c0 + 0][r] = __float2bfloat16(vv.x);
    tile[c0 + 1][r] = __float2bfloat16(vv.y);
    tile[c0 + 2][r] = __float2bfloat16(vv.z);
    tile[c0 + 3][r] = __float2bfloat16(vv.w);
  }
  __syncthreads();
#pragma unroll
  for (int p = 0; p < 2; ++p) {
    int idx = p * 2048 + t * 8;
    int c = idx >> 6, r0 = idx & 63;
    *(uint4*)&out[(size_t)(bx + c) * 1024 + by + r0] = *(const uint4*)&tile[c][r0];
  }
}

// ---------------------------------------------------------------------------
// QKV GEMM: A bf16 [4096x1024], Bt = W^T [N][K] bf16.
// BK=64 (R9's KVBLK-doubling transform ported): K-tile stored as two
// 32-wide sub-tiles so staging/fragment reads are identical to the proven
// BK=32 code; 16 K-steps instead of 32 -> 32 MFMA/wave per barrier instead
// of 16, barrier+drain count halved at the same staged bytes. Double-buffer,
// 1-ahead prefetch, vmcnt(0)+barrier after compute (attn-R9 scheme).
// LDS 64 KB -> 2 blocks/CU. Grid (32,8,3) 2D (natural bm-major order: 32
// consecutive blocks share one B-panel in L2).
// z: 0=Q (QSCL folded), 1=K (head-split), 2=V (split+transpose, 8B stores).
// ---------------------------------------------------------------------------
__global__ __launch_bounds__(256, 2) void gemm_qkv_bf16(
    const bf16* __restrict__ Aq, const bf16* __restrict__ Ak,
    const bf16* __restrict__ Av,
    const bf16* __restrict__ WtQ, const bf16* __restrict__ WtK,
    const bf16* __restrict__ WtV,
    const float* __restrict__ bq, const float* __restrict__ bk_,
    const float* __restrict__ bv_,
    bf16* __restrict__ Qh, bf16* __restrict__ Kh, bf16* __restrict__ Vt) {
  constexpr int K = 1024;
  const int z = blockIdx.z;
  const bf16* A    = (z == 0) ? Aq : (z == 1) ? Ak : Av;
  const bf16* Bt   = (z == 0) ? WtQ : (z == 1) ? WtK : WtV;
  const float* bias = (z == 0) ? bq : (z == 1) ? bk_ : bv_;
  bf16* C = (z == 0) ? Qh : (z == 1) ? Kh : Vt;

  __shared__ alignas(16) bf16 As[2][2][128 * 32];  // [buf][sub][...]
  __shared__ alignas(16) bf16 Bs[2][2][128 * 32];
  const int t = threadIdx.x;
  const int wave = t >> 6, lane = t & 63;
  const int quad = lane >> 4, l16 = lane & 15;
  const int bm = blockIdx.x * 128, bn = blockIdx.y * 128;
  const int wm = (wave & 1) * 64, wn = (wave >> 1) * 64;

  f32x4v acc[4][4] = {};

  auto stage = [&](int ks, int buf) {  // ks = 64-wide K-step 0..15; 8 g2l16
    int k0 = ks * 64;
#pragma unroll
    for (int sub = 0; sub < 2; ++sub)
#pragma unroll
      for (int c = 0; c < 2; ++c) {
        int idx2 = c * 2048 + t * 8;
        int row = idx2 >> 5, col = idx2 & 31;
        g2l16(&A[(size_t)(bm + row) * K + k0 + sub * 32 + col],
              &As[buf][sub][c * 2048 + wave * 512]);
        g2l16(&Bt[(size_t)(bn + row) * K + k0 + sub * 32 + col],
              &Bs[buf][sub][c * 2048 + wave * 512]);
      }
  };

  auto compute = [&](int buf) {
#pragma unroll
    for (int kk = 0; kk < 2; ++kk) {
      bf16x8v a[4], b[4];
#pragma unroll
      for (int mi = 0; mi < 4; ++mi)
        a[mi] = *(const bf16x8v*)&As[buf][kk][(wm + mi * 16 + l16) * 32 + quad * 8];
#pragma unroll
      for (int ni = 0; ni < 4; ++ni)
        b[ni] = *(const bf16x8v*)&Bs[buf][kk][(wn + ni * 16 + l16) * 32 + quad * 8];
#pragma unroll
      for (int mi = 0; mi < 4; ++mi)
#pragma unroll
        for (int ni = 0; ni < 4; ++ni)
          acc[mi][ni] = __builtin_amdgcn_mfma_f32_16x16x32_bf16(a[mi], b[ni],
                                                                acc[mi][ni],
                                                                0, 0, 0);
    }
  };

  stage(0, 0);
  asm volatile("s_waitcnt vmcnt(0)" ::: "memory");
  __builtin_amdgcn_s_barrier();
  for (int tt = 0; tt < 16; ++tt) {
    if (tt < 15) stage(tt + 1, (tt + 1) & 1);  // hidden under compute(tt)
    compute(tt & 1);
    if (tt < 15) {
      asm volatile("s_waitcnt vmcnt(0)" ::: "memory");
      __builtin_amdgcn_s_barrier();
    }
  }

  if (z == 2) {
    // V^T store: s = m&2047 contiguous along r -> pack 4 bf16 per 8B store
#pragma unroll
    for (int ni = 0; ni < 4; ++ni) {
      int n = bn + wn + ni * 16 + l16;
      float bz = bias[n];
      int h_ = n >> 6, d_ = n & 63;
#pragma unroll
      for (int mi = 0; mi < 4; ++mi) {
        int m0 = bm + wm + mi * 16 + quad * 4;
        int b_ = m0 >> 11, s0 = m0 & 2047;
        uint2 u;
        u.x = packbf(fclamp(acc[mi][ni][0] + bz), fclamp(acc[mi][ni][1] + bz));
        u.y = packbf(fclamp(acc[mi][ni][2] + bz), fclamp(acc[mi][ni][3] + bz));
        *(uint2*)&C[((size_t)(b_ * 16 + h_) * 64 + d_) * 2048 + s0] = u;
      }
    }
  } else {
    const float scl = (z == 0) ? QSCL : 1.0f;  // fold softmax scale into Q
#pragma unroll
    for (int ni = 0; ni < 4; ++ni) {
      int n = bn + wn + ni * 16 + l16;
      float bz = bias[n];
      int h_ = n >> 6, d_ = n & 63;
#pragma unroll
      for (int mi = 0; mi < 4; ++mi)
#pragma unroll
        for (int r = 0; r < 4; ++r) {
          int m = bm + wm + mi * 16 + quad * 4 + r;
          int b_ = m >> 11, s_ = m & 2047;
          C[((size_t)(b_ * 16 + h_) * 2048 + s_) * 64 + d_] =
              __float2bfloat16(fclamp(acc[mi][ni][r] + bz) * scl);
        }
    }
  }
}

// ---------------------------------------------------------------------------
// Output projection: 128x64 tile, BK=64 (same transform), double-buffered
// 1-ahead, vmcnt(0)+barrier. LDS 48 KB. Grid (32,16) 2D.
// ---------------------------------------------------------------------------
__global__ __launch_bounds__(256, 2) void gemm_out(
    const bf16* __restrict__ A, const bf16* __restrict__ Bt,
    const float* __restrict__ bias, float* __restrict__ C) {
  constexpr int K = 1024, N = 1024;
  __shared__ alignas(16) bf16 As[2][2][128 * 32];
  __shared__ alignas(16) bf16 Bs[2][2][64 * 32];
  const int t = threadIdx.x;
  const int wave = t >> 6, lane = t & 63;
  const int quad = lane >> 4, l16 = lane & 15;
  const int bm = blockIdx.x * 128, bn = blockIdx.y * 64;
  const int wm = (wave & 1) * 64, wn = (wave >> 1) * 32;

  f32x4v acc[4][2] = {};

  auto stage = [&](int ks, int buf) {  // 6 g2l16/thread
    int k0 = ks * 64;
#pragma unroll
    for (int sub = 0; sub < 2; ++sub) {
#pragma unroll
      for (int c = 0; c < 2; ++c) {
        int idx2 = c * 2048 + t * 8;
        int row = idx2 >> 5, col = idx2 & 31;
        g2l16(&A[(size_t)(bm + row) * K + k0 + sub * 32 + col],
              &As[buf][sub][c * 2048 + wave * 512]);
      }
      int idx2 = t * 8;
      int row = idx2 >> 5, col = idx2 & 31;
      g2l16(&Bt[(size_t)(bn + row) * K + k0 + sub * 32 + col],
            &Bs[buf][sub][wave * 512]);
    }
  };

  auto compute = [&](int buf) {
#pragma unroll
    for (int kk = 0; kk < 2; ++kk) {
      bf16x8v a[4], b[2];
#pragma unroll
      for (int mi = 0; mi < 4; ++mi)
        a[mi] = *(const bf16x8v*)&As[buf][kk][(wm + mi * 16 + l16) * 32 + quad * 8];
#pragma unroll
      for (int ni = 0; ni < 2; ++ni)
        b[ni] = *(const bf16x8v*)&Bs[buf][kk][(wn + ni * 16 + l16) * 32 + quad * 8];
#pragma unroll
      for (int mi = 0; mi < 4; ++mi)
#pragma unroll
        for (int ni = 0; ni < 2; ++ni)
          acc[mi][ni] = __builtin_amdgcn_mfma_f32_16x16x32_bf16(a[mi], b[ni],
                                                                acc[mi][ni],
                                                                0, 0, 0);
    }
  };

  stage(0, 0);
  asm volatile("s_waitcnt vmcnt(0)" ::: "memory");
  __builtin_amdgcn_s_barrier();
  for (int tt = 0; tt < 16; ++tt) {
    if (tt < 15) stage(tt + 1, (tt + 1) & 1);
    compute(tt & 1);
    if (tt < 15) {
      asm volatile("s_waitcnt vmcnt(0)" ::: "memory");
      __builtin_amdgcn_s_barrier();
    }
  }

#pragma unroll
  for (int ni = 0; ni < 2; ++ni) {
    int n = bn + wn + ni * 16 + l16;
    float bz = bias[n];
#pragma unroll
    for (int mi = 0; mi < 4; ++mi)
#pragma unroll
      for (int r = 0; r < 4; ++r) {
        int m = bm + wm + mi * 16 + quad * 4 + r;
        C[(size_t)m * N + n] = fclamp(acc[mi][ni][r] + bz);
      }
  }
}

// ---------------------------------------------------------------------------
// Flash attention v10 (best measured: 57.5-58.2 us): KVBLK=128, 16 tiles of
// 128 keys (4 h-phases each), 512-thr blocks, XCD-bijective decode,
// 2-buffer 1-ahead prefetch, swapped QK^T + packed b64 P-store, Qs/Ps
// union, Q-hoist, MFMA row-sum, setprio, XOR chunk swizzle. LDS 80 KB.
// ---------------------------------------------------------------------------
__global__ __launch_bounds__(512, 4) void attn(
    const bf16* __restrict__ Qh, const bf16* __restrict__ Kh,
    const bf16* __restrict__ Vt, bf16* __restrict__ Ctx) {
  constexpr int LDPP = 40;  // Ps row stride (16B-aligned rows: 80 B)
  __shared__ alignas(16) bf16 QsPs[128 * 64];   // Qs (prologue) / Ps (loop)
  __shared__ alignas(16) bf16 Ks[2][128 * 64];  // [buf][hc*4096 + r64*64 + c]
  __shared__ alignas(16) bf16 Vs[2][128 * 64];  // [buf][hc*4096 + d64*64 + k]
  const int t = threadIdx.x;
  const int wave = t >> 6, lane = t & 63;  // wave 0..7
  const int quad = lane >> 4, l16 = lane & 15;
  const int sw = l16 & 7;  // per-lane chunk swizzle key (row&7 == l16&7)

  // XCD-bijective decode: lin%8 = XCD; each XCD gets 4 bh x 16 qb.
  const int lin = blockIdx.x;       // 0..511
  const int li = lin >> 3;          // 0..63
  const int qb = li & 15;           // 0..15
  const int bh = (lin & 7) * 4 + (li >> 4);  // 0..31

  const size_t bh_off = (size_t)bh * 2048 * 64;
  const bf16* Qb = Qh + bh_off;
  const bf16* Kb = Kh + bh_off;
  const bf16* Vb = Vt + bh_off;  // [64][2048]

  // staging coords: 512 threads cover one 64x64 sub-tile per pass
  const int srow = t >> 3;   // 0..63
  const int schunk = t & 7;

  auto stageKV = [&](int kt, int buf) {  // kt = 128-key tile 0..15
    int mc = schunk ^ (srow & 7);
#pragma unroll
    for (int c = 0; c < 2; ++c) {  // key-half sub-tiles
      g2l16(&Kb[(size_t)(kt * 128 + c * 64 + srow) * 64 + mc * 8],
            &Ks[buf][c * 4096 + wave * 512]);
      g2l16(&Vb[(size_t)srow * 2048 + kt * 128 + c * 64 + mc * 8],
            &Vs[buf][c * 4096 + wave * 512]);
    }
  };

  // prologue: Q (2 loads) then tile 0 (4 loads); vmcnt(4) -> Q done.
#pragma unroll
  for (int c = 0; c < 2; ++c) {
    int row = c * 64 + srow;
    int mc = schunk ^ (row & 7);
    g2l16(&Qb[(size_t)(qb * 128 + row) * 64 + mc * 8],
          &QsPs[c * 4096 + wave * 512]);
  }
  stageKV(0, 0);
  asm volatile("s_waitcnt vmcnt(4)" ::: "memory");
  __builtin_amdgcn_s_barrier();

  // Q-hoist: fragments are kt-invariant, keep in registers (8 VGPR)
  bf16x8v aq[2];  // [kk]
#pragma unroll
  for (int kk = 0; kk < 2; ++kk)
    aq[kk] = *(const bf16x8v*)
        &QsPs[(wave * 16 + l16) * 64 + (((kk * 4 + quad) ^ sw) << 3)];

  // Qs region now dead -> reuse as Ps. __syncthreads drains vmcnt too,
  // so tile 0 is fully resident past this point.
  __syncthreads();
  bf16* Psw = QsPs + wave * (16 * LDPP);  // per-wave P buffer (1280 B)

  // all-ones B fragment for MFMA row-sum
  bf16x8v vone;
#pragma unroll
  for (int i = 0; i < 8; ++i) vone[i] = (__bf16)1.0f;

  f32x4v lsum = {};
  f32x4v oacc[4] = {};

  auto compute = [&](int buf) {
#pragma unroll
    for (int h = 0; h < 4; ++h) {  // four 32-key phases per 128-key tile
      const int hc = h >> 1, hl = h & 1;
      // S^T = K(32x64) x Q^T(64x16): row=key(quad*4+r), col=q(l16)
      f32x4v s[2] = {};  // [ni]
      __builtin_amdgcn_s_setprio(1);
#pragma unroll
      for (int kk = 0; kk < 2; ++kk)
#pragma unroll
        for (int ni = 0; ni < 2; ++ni) {
          bf16x8v bk = *(const bf16x8v*)
              &Ks[buf][hc * 4096 + (hl * 32 + ni * 16 + l16) * 64 +
                       (((kk * 4 + quad) ^ sw) << 3)];
          s[ni] = __builtin_amdgcn_mfma_f32_16x16x32_bf16(bk, aq[kk],
                                                          s[ni], 0, 0, 0);
        }
      __builtin_amdgcn_s_setprio(0);

      // P = exp2(S); 4 consecutive keys/lane -> pack -> one b64 write each.
#pragma unroll
      for (int ni = 0; ni < 2; ++ni) {
        float p0 = __builtin_amdgcn_exp2f(fminf(s[ni][0], 80.f));
        float p1 = __builtin_amdgcn_exp2f(fminf(s[ni][1], 80.f));
        float p2 = __builtin_amdgcn_exp2f(fminf(s[ni][2], 80.f));
        float p3 = __builtin_amdgcn_exp2f(fminf(s[ni][3], 80.f));
        uint2 u;
        u.x = packbf(p0, p1);
        u.y = packbf(p2, p3);
        *(uint2*)&Psw[l16 * LDPP + ni * 16 + quad * 4] = u;
      }

      // O += P(16x32) x V(32x64); l += P x ones (row-sum on matrix pipe)
      bf16x8v ap = *(const bf16x8v*)&Psw[l16 * LDPP + quad * 8];
      __builtin_amdgcn_s_setprio(1);
      lsum = __builtin_amdgcn_mfma_f32_16x16x32_bf16(ap, vone, lsum, 0, 0, 0);
#pragma unroll
      for (int ni = 0; ni < 4; ++ni) {
        bf16x8v bv = *(const bf16x8v*)
            &Vs[buf][hc * 4096 + (ni * 16 + l16) * 64 +
                     (((hl * 4 + quad) ^ sw) << 3)];
        oacc[ni] = __builtin_amdgcn_mfma_f32_16x16x32_bf16(ap, bv, oacc[ni],
                                                           0, 0, 0);
      }
      __builtin_amdgcn_s_setprio(0);
    }
  };

  // main loop: stage(t+1) at top -> compute(t) -> vmcnt(0)+barrier.
  for (int tt = 0; tt < 16; ++tt) {
    if (tt + 1 < 16) stageKV(tt + 1, (tt + 1) & 1);
    compute(tt & 1);
    if (tt + 1 < 16) {
      asm volatile("s_waitcnt vmcnt(0)" ::: "memory");
      __builtin_amdgcn_s_barrier();
    }
  }

  // epilogue: O / l -> Ctx[b][s][h*64+dh]
  const int b_ = bh >> 4, h_ = bh & 15;
#pragma unroll
  for (int r = 0; r < 4; ++r) {
    int sr = qb * 128 + wave * 16 + quad * 4 + r;
    float inv = 1.0f / fmaxf(lsum[r], 1.0e-20f);
#pragma unroll
    for (int ni = 0; ni < 4; ++ni) {
      int col = h_ * 64 + ni * 16 + l16;
      Ctx[(size_t)(b_ * 2048 + sr) * 1024 + col] =
          __float2bfloat16(fclamp(oacc[ni][r] * inv));
    }
  }
}

extern "C" void kernel_launch(void* const* d_in, const int* in_sizes, int n_in,
                              void* d_out, int out_size, void* d_ws, size_t ws_size,
                              hipStream_t stream) {
  const float* q   = (const float*)d_in[0];
  const float* k   = (const float*)d_in[1];
  const float* v   = (const float*)d_in[2];
  const float* w_q = (const float*)d_in[3];
  const float* b_q = (const float*)d_in[4];
  const float* w_k = (const float*)d_in[5];
  const float* b_k = (const float*)d_in[6];
  const float* w_v = (const float*)d_in[7];
  const float* b_v = (const float*)d_in[8];
  const float* w_o = (const float*)d_in[9];
  const float* b_o = (const float*)d_in[10];
  float* out = (float*)d_out;

  char* ws = (char*)d_ws;
  const size_t MB = (size_t)1024 * 1024;
  bf16* WtQ = (bf16*)(ws + 0 * MB);
  bf16* WtK = (bf16*)(ws + 2 * MB);
  bf16* WtV = (bf16*)(ws + 4 * MB);
  bf16* WtO = (bf16*)(ws + 6 * MB);
  bf16* Qa  = (bf16*)(ws + 8 * MB);   // bf16 activations (8 MiB each)
  bf16* Ka  = (bf16*)(ws + 16 * MB);
  bf16* Va  = (bf16*)(ws + 24 * MB);
  bf16* Qh  = (bf16*)(ws + 32 * MB);  // [2,16,2048,64]
  bf16* Kh  = (bf16*)(ws + 40 * MB);
  bf16* Vt  = (bf16*)(ws + 48 * MB);  // [2,16,64,2048]
  bf16* Ctx = Qa;                     // Qa dead after gemm_qkv

  dim3 tb(256);
  prep<<<dim3(7168), tb, 0, stream>>>(q, k, v, w_q, w_k, w_v, w_o,
                                      Qa, Ka, Va, WtQ, WtK, WtV, WtO);
  gemm_qkv_bf16<<<dim3(32, 8, 3), tb, 0, stream>>>(Qa, Ka, Va, WtQ, WtK, WtV,
                                                   b_q, b_k, b_v, Qh, Kh, Vt);
  attn<<<dim3(512), dim3(512), 0, stream>>>(Qh, Kh, Vt, Ctx);
  gemm_out<<<dim3(32, 16), tb, 0, stream>>>(Ctx, WtO, b_o, out);
}

// Round 13
// 219.259 us; speedup vs baseline: 1.0655x; 1.0655x over previous
//
#include <hip/hip_runtime.h>
#include <hip/hip_bf16.h>
#include <math.h>

using bf16 = __hip_bfloat16;
typedef __bf16 bf16x8v __attribute__((ext_vector_type(8)));
typedef float f32x4v __attribute__((ext_vector_type(4)));

#define AS1 __attribute__((address_space(1)))
#define AS3 __attribute__((address_space(3)))

// async global->LDS, 16B/lane; LDS dest = wave-uniform base + lane*16
__device__ __forceinline__ void g2l16(const void* g, void* l) {
  __builtin_amdgcn_global_load_lds((const AS1 void*)g, (AS3 void*)l, 16, 0, 0);
}

__device__ __forceinline__ float fclamp(float v) {
  return fminf(fmaxf(v, -6.0e4f), 6.0e4f);  // NaN firewall
}

// pack two floats to adjacent bf16 (compiler emits v_cvt_pk_bf16_f32)
__device__ __forceinline__ unsigned packbf(float a, float b) {
  unsigned short lo = __builtin_bit_cast(unsigned short, __float2bfloat16(a));
  unsigned short hi = __builtin_bit_cast(unsigned short, __float2bfloat16(b));
  return (unsigned)lo | ((unsigned)hi << 16);
}

// scale*log2(e), folded into Q projection so attn uses plain exp2
#define QSCL 0.1803368801111204f

// ---------------------------------------------------------------------------
// Merged prep: activations fp32->bf16 (lin < 6144) + weight transpose+cvt
// (lin >= 6144).
// ---------------------------------------------------------------------------
__global__ __launch_bounds__(256) void prep(
    const float* __restrict__ q, const float* __restrict__ k,
    const float* __restrict__ v,
    const float* __restrict__ w0, const float* __restrict__ w1,
    const float* __restrict__ w2, const float* __restrict__ w3,
    bf16* __restrict__ oq, bf16* __restrict__ ok, bf16* __restrict__ ov,
    bf16* __restrict__ o0, bf16* __restrict__ o1,
    bf16* __restrict__ o2, bf16* __restrict__ o3) {
  __shared__ alignas(16) bf16 tile[64][80];
  const int t = threadIdx.x;
  const int lin = blockIdx.x;
  if (lin < 6144) {  // cvt path: 3 tensors x 2048 blocks
    const int tensor = lin >> 11, blk = lin & 2047;
    const float* in = (tensor == 0) ? q : (tensor == 1) ? k : v;
    bf16* out = (tensor == 0) ? oq : (tensor == 1) ? ok : ov;
    int i = (blk * 256 + t) * 8;
    float4 a = *(const float4*)&in[i];
    float4 b = *(const float4*)&in[i + 4];
    uint4 u;
    u.x = packbf(a.x, a.y); u.y = packbf(a.z, a.w);
    u.z = packbf(b.x, b.y); u.w = packbf(b.z, b.w);
    *(uint4*)&out[i] = u;
    return;
  }
  // transpose path: 4 weights x 256 tiles
  const int rem = lin - 6144;
  const int z = rem >> 8, xy = rem & 255;
  const float* in = (z == 0) ? w0 : (z == 1) ? w1 : (z == 2) ? w2 : w3;
  bf16* out = (z == 0) ? o0 : (z == 1) ? o1 : (z == 2) ? o2 : o3;
  const int bx = (xy & 15) * 64, by = (xy >> 4) * 64;
#pragma unroll
  for (int p = 0; p < 4; ++p) {
    int idx = p * 1024 + t * 4;
    int r = idx >> 6, c0 = idx & 63;
    float4 vv = *(const float4*)&in[(size_t)(by + r) * 1024 + bx + c0];
    tile[c0 + 0][r] = __float2bfloat16(vv.x);
    tile[c0 + 1][r] = __float2bfloat16(vv.y);
    tile[c0 + 2][r] = __float2bfloat16(vv.z);
    tile[c0 + 3][r] = __float2bfloat16(vv.w);
  }
  __syncthreads();
#pragma unroll
  for (int p = 0; p < 2; ++p) {
    int idx = p * 2048 + t * 8;
    int c = idx >> 6, r0 = idx & 63;
    *(uint4*)&out[(size_t)(bx + c) * 1024 + by + r0] = *(const uint4*)&tile[c][r0];
  }
}

// ---------------------------------------------------------------------------
// QKV GEMM: A bf16 [4096x1024], Bt = W^T [N][K] bf16.
// Triple-buffered 2-ahead pipeline, counted vmcnt(4) (best-measured GEMM
// form this session, R9: 223.8 total). LDS 48 KB, grid (32,8,3).
// z: 0=Q (QSCL folded), 1=K (head-split), 2=V (split+transpose, 8B stores).
// ---------------------------------------------------------------------------
__global__ __launch_bounds__(256, 2) void gemm_qkv_bf16(
    const bf16* __restrict__ Aq, const bf16* __restrict__ Ak,
    const bf16* __restrict__ Av,
    const bf16* __restrict__ WtQ, const bf16* __restrict__ WtK,
    const bf16* __restrict__ WtV,
    const float* __restrict__ bq, const float* __restrict__ bk_,
    const float* __restrict__ bv_,
    bf16* __restrict__ Qh, bf16* __restrict__ Kh, bf16* __restrict__ Vt) {
  constexpr int K = 1024;
  const int z = blockIdx.z;
  const bf16* A    = (z == 0) ? Aq : (z == 1) ? Ak : Av;
  const bf16* Bt   = (z == 0) ? WtQ : (z == 1) ? WtK : WtV;
  const float* bias = (z == 0) ? bq : (z == 1) ? bk_ : bv_;
  bf16* C = (z == 0) ? Qh : (z == 1) ? Kh : Vt;

  __shared__ alignas(16) bf16 As[3][128 * 32];
  __shared__ alignas(16) bf16 Bs[3][128 * 32];
  const int t = threadIdx.x;
  const int wave = t >> 6, lane = t & 63;
  const int quad = lane >> 4, l16 = lane & 15;
  const int bm = blockIdx.x * 128, bn = blockIdx.y * 128;
  const int wm = (wave & 1) * 64, wn = (wave >> 1) * 64;

  f32x4v acc[4][4] = {};

  auto stage = [&](int ks, int buf) {  // 4 g2l16/thread
    int k0 = ks * 32;
#pragma unroll
    for (int c = 0; c < 2; ++c) {
      int idx2 = c * 2048 + t * 8;
      int row = idx2 >> 5, col = idx2 & 31;
      g2l16(&A[(size_t)(bm + row) * K + k0 + col], &As[buf][c * 2048 + wave * 512]);
      g2l16(&Bt[(size_t)(bn + row) * K + k0 + col], &Bs[buf][c * 2048 + wave * 512]);
    }
  };

  auto compute = [&](int buf) {
    bf16x8v a[4], b[4];
#pragma unroll
    for (int mi = 0; mi < 4; ++mi)
      a[mi] = *(const bf16x8v*)&As[buf][(wm + mi * 16 + l16) * 32 + quad * 8];
#pragma unroll
    for (int ni = 0; ni < 4; ++ni)
      b[ni] = *(const bf16x8v*)&Bs[buf][(wn + ni * 16 + l16) * 32 + quad * 8];
#pragma unroll
    for (int mi = 0; mi < 4; ++mi)
#pragma unroll
      for (int ni = 0; ni < 4; ++ni)
        acc[mi][ni] = __builtin_amdgcn_mfma_f32_16x16x32_bf16(a[mi], b[ni],
                                                              acc[mi][ni], 0, 0, 0);
  };

  stage(0, 0);
  asm volatile("s_waitcnt vmcnt(0)" ::: "memory");
  __builtin_amdgcn_s_barrier();
  stage(1, 1);

  int bufc = 0;
  for (int tt = 0; tt < 30; ++tt) {
    int bufs = bufc + 2; if (bufs >= 3) bufs -= 3;
    stage(tt + 2, bufs);
    compute(bufc);
    asm volatile("s_waitcnt vmcnt(4)" ::: "memory");
    __builtin_amdgcn_s_barrier();
    bufc = (bufc == 2) ? 0 : bufc + 1;
  }
  compute(bufc);
  asm volatile("s_waitcnt vmcnt(0)" ::: "memory");
  __builtin_amdgcn_s_barrier();
  bufc = (bufc == 2) ? 0 : bufc + 1;
  compute(bufc);

  if (z == 2) {
    // V^T store: s = m&2047 contiguous along r -> pack 4 bf16 per 8B store
#pragma unroll
    for (int ni = 0; ni < 4; ++ni) {
      int n = bn + wn + ni * 16 + l16;
      float bz = bias[n];
      int h_ = n >> 6, d_ = n & 63;
#pragma unroll
      for (int mi = 0; mi < 4; ++mi) {
        int m0 = bm + wm + mi * 16 + quad * 4;
        int b_ = m0 >> 11, s0 = m0 & 2047;
        uint2 u;
        u.x = packbf(fclamp(acc[mi][ni][0] + bz), fclamp(acc[mi][ni][1] + bz));
        u.y = packbf(fclamp(acc[mi][ni][2] + bz), fclamp(acc[mi][ni][3] + bz));
        *(uint2*)&C[((size_t)(b_ * 16 + h_) * 64 + d_) * 2048 + s0] = u;
      }
    }
  } else {
    const float scl = (z == 0) ? QSCL : 1.0f;  // fold softmax scale into Q
#pragma unroll
    for (int ni = 0; ni < 4; ++ni) {
      int n = bn + wn + ni * 16 + l16;
      float bz = bias[n];
      int h_ = n >> 6, d_ = n & 63;
#pragma unroll
      for (int mi = 0; mi < 4; ++mi)
#pragma unroll
        for (int r = 0; r < 4; ++r) {
          int m = bm + wm + mi * 16 + quad * 4 + r;
          int b_ = m >> 11, s_ = m & 2047;
          C[((size_t)(b_ * 16 + h_) * 2048 + s_) * 64 + d_] =
              __float2bfloat16(fclamp(acc[mi][ni][r] + bz) * scl);
        }
    }
  }
}

// ---------------------------------------------------------------------------
// Output projection: 128x64 tile, triple-buffered 2-ahead pipeline,
// counted vmcnt(3). LDS 36 KB. Grid (32,16).
// ---------------------------------------------------------------------------
__global__ __launch_bounds__(256, 2) void gemm_out(
    const bf16* __restrict__ A, const bf16* __restrict__ Bt,
    const float* __restrict__ bias, float* __restrict__ C) {
  constexpr int K = 1024, N = 1024;
  __shared__ alignas(16) bf16 As[3][128 * 32];
  __shared__ alignas(16) bf16 Bs[3][64 * 32];
  const int t = threadIdx.x;
  const int wave = t >> 6, lane = t & 63;
  const int quad = lane >> 4, l16 = lane & 15;
  const int bm = blockIdx.x * 128, bn = blockIdx.y * 64;
  const int wm = (wave & 1) * 64, wn = (wave >> 1) * 32;

  f32x4v acc[4][2] = {};

  auto stage = [&](int ks, int buf) {  // 3 g2l16/thread
    int k0 = ks * 32;
#pragma unroll
    for (int c = 0; c < 2; ++c) {
      int idx2 = c * 2048 + t * 8;
      int row = idx2 >> 5, col = idx2 & 31;
      g2l16(&A[(size_t)(bm + row) * K + k0 + col], &As[buf][c * 2048 + wave * 512]);
    }
    {
      int idx2 = t * 8;
      int row = idx2 >> 5, col = idx2 & 31;
      g2l16(&Bt[(size_t)(bn + row) * K + k0 + col], &Bs[buf][wave * 512]);
    }
  };

  auto compute = [&](int buf) {
    bf16x8v a[4], b[2];
#pragma unroll
    for (int mi = 0; mi < 4; ++mi)
      a[mi] = *(const bf16x8v*)&As[buf][(wm + mi * 16 + l16) * 32 + quad * 8];
#pragma unroll
    for (int ni = 0; ni < 2; ++ni)
      b[ni] = *(const bf16x8v*)&Bs[buf][(wn + ni * 16 + l16) * 32 + quad * 8];
#pragma unroll
    for (int mi = 0; mi < 4; ++mi)
#pragma unroll
      for (int ni = 0; ni < 2; ++ni)
        acc[mi][ni] = __builtin_amdgcn_mfma_f32_16x16x32_bf16(a[mi], b[ni],
                                                              acc[mi][ni], 0, 0, 0);
  };

  stage(0, 0);
  asm volatile("s_waitcnt vmcnt(0)" ::: "memory");
  __builtin_amdgcn_s_barrier();
  stage(1, 1);

  int bufc = 0;
  for (int tt = 0; tt < 30; ++tt) {
    int bufs = bufc + 2; if (bufs >= 3) bufs -= 3;
    stage(tt + 2, bufs);
    compute(bufc);
    asm volatile("s_waitcnt vmcnt(3)" ::: "memory");
    __builtin_amdgcn_s_barrier();
    bufc = (bufc == 2) ? 0 : bufc + 1;
  }
  compute(bufc);
  asm volatile("s_waitcnt vmcnt(0)" ::: "memory");
  __builtin_amdgcn_s_barrier();
  bufc = (bufc == 2) ? 0 : bufc + 1;
  compute(bufc);

#pragma unroll
  for (int ni = 0; ni < 2; ++ni) {
    int n = bn + wn + ni * 16 + l16;
    float bz = bias[n];
#pragma unroll
    for (int mi = 0; mi < 4; ++mi)
#pragma unroll
      for (int r = 0; r < 4; ++r) {
        int m = bm + wm + mi * 16 + quad * 4 + r;
        C[(size_t)m * N + n] = fclamp(acc[mi][ni][r] + bz);
      }
  }
}

// ---------------------------------------------------------------------------
// Flash attention v10 (best measured: 57.5-58.2 us): KVBLK=128, 16 tiles of
// 128 keys (4 h-phases each), 512-thr blocks, XCD-bijective decode,
// 2-buffer 1-ahead prefetch, swapped QK^T + packed b64 P-store, Qs/Ps
// union, Q-hoist, MFMA row-sum, setprio, XOR chunk swizzle. LDS 80 KB.
// ---------------------------------------------------------------------------
__global__ __launch_bounds__(512, 4) void attn(
    const bf16* __restrict__ Qh, const bf16* __restrict__ Kh,
    const bf16* __restrict__ Vt, bf16* __restrict__ Ctx) {
  constexpr int LDPP = 40;  // Ps row stride (16B-aligned rows: 80 B)
  __shared__ alignas(16) bf16 QsPs[128 * 64];   // Qs (prologue) / Ps (loop)
  __shared__ alignas(16) bf16 Ks[2][128 * 64];  // [buf][hc*4096 + r64*64 + c]
  __shared__ alignas(16) bf16 Vs[2][128 * 64];  // [buf][hc*4096 + d64*64 + k]
  const int t = threadIdx.x;
  const int wave = t >> 6, lane = t & 63;  // wave 0..7
  const int quad = lane >> 4, l16 = lane & 15;
  const int sw = l16 & 7;  // per-lane chunk swizzle key (row&7 == l16&7)

  // XCD-bijective decode: lin%8 = XCD; each XCD gets 4 bh x 16 qb.
  const int lin = blockIdx.x;       // 0..511
  const int li = lin >> 3;          // 0..63
  const int qb = li & 15;           // 0..15
  const int bh = (lin & 7) * 4 + (li >> 4);  // 0..31

  const size_t bh_off = (size_t)bh * 2048 * 64;
  const bf16* Qb = Qh + bh_off;
  const bf16* Kb = Kh + bh_off;
  const bf16* Vb = Vt + bh_off;  // [64][2048]

  // staging coords: 512 threads cover one 64x64 sub-tile per pass
  const int srow = t >> 3;   // 0..63
  const int schunk = t & 7;

  auto stageKV = [&](int kt, int buf) {  // kt = 128-key tile 0..15
    int mc = schunk ^ (srow & 7);
#pragma unroll
    for (int c = 0; c < 2; ++c) {  // key-half sub-tiles
      g2l16(&Kb[(size_t)(kt * 128 + c * 64 + srow) * 64 + mc * 8],
            &Ks[buf][c * 4096 + wave * 512]);
      g2l16(&Vb[(size_t)srow * 2048 + kt * 128 + c * 64 + mc * 8],
            &Vs[buf][c * 4096 + wave * 512]);
    }
  };

  // prologue: Q (2 loads) then tile 0 (4 loads); vmcnt(4) -> Q done.
#pragma unroll
  for (int c = 0; c < 2; ++c) {
    int row = c * 64 + srow;
    int mc = schunk ^ (row & 7);
    g2l16(&Qb[(size_t)(qb * 128 + row) * 64 + mc * 8],
          &QsPs[c * 4096 + wave * 512]);
  }
  stageKV(0, 0);
  asm volatile("s_waitcnt vmcnt(4)" ::: "memory");
  __builtin_amdgcn_s_barrier();

  // Q-hoist: fragments are kt-invariant, keep in registers (8 VGPR)
  bf16x8v aq[2];  // [kk]
#pragma unroll
  for (int kk = 0; kk < 2; ++kk)
    aq[kk] = *(const bf16x8v*)
        &QsPs[(wave * 16 + l16) * 64 + (((kk * 4 + quad) ^ sw) << 3)];

  // Qs region now dead -> reuse as Ps. __syncthreads drains vmcnt too,
  // so tile 0 is fully resident past this point.
  __syncthreads();
  bf16* Psw = QsPs + wave * (16 * LDPP);  // per-wave P buffer (1280 B)

  // all-ones B fragment for MFMA row-sum
  bf16x8v vone;
#pragma unroll
  for (int i = 0; i < 8; ++i) vone[i] = (__bf16)1.0f;

  f32x4v lsum = {};
  f32x4v oacc[4] = {};

  auto compute = [&](int buf) {
#pragma unroll
    for (int h = 0; h < 4; ++h) {  // four 32-key phases per 128-key tile
      const int hc = h >> 1, hl = h & 1;
      // S^T = K(32x64) x Q^T(64x16): row=key(quad*4+r), col=q(l16)
      f32x4v s[2] = {};  // [ni]
      __builtin_amdgcn_s_setprio(1);
#pragma unroll
      for (int kk = 0; kk < 2; ++kk)
#pragma unroll
        for (int ni = 0; ni < 2; ++ni) {
          bf16x8v bk = *(const bf16x8v*)
              &Ks[buf][hc * 4096 + (hl * 32 + ni * 16 + l16) * 64 +
                       (((kk * 4 + quad) ^ sw) << 3)];
          s[ni] = __builtin_amdgcn_mfma_f32_16x16x32_bf16(bk, aq[kk],
                                                          s[ni], 0, 0, 0);
        }
      __builtin_amdgcn_s_setprio(0);

      // P = exp2(S); 4 consecutive keys/lane -> pack -> one b64 write each.
#pragma unroll
      for (int ni = 0; ni < 2; ++ni) {
        float p0 = __builtin_amdgcn_exp2f(fminf(s[ni][0], 80.f));
        float p1 = __builtin_amdgcn_exp2f(fminf(s[ni][1], 80.f));
        float p2 = __builtin_amdgcn_exp2f(fminf(s[ni][2], 80.f));
        float p3 = __builtin_amdgcn_exp2f(fminf(s[ni][3], 80.f));
        uint2 u;
        u.x = packbf(p0, p1);
        u.y = packbf(p2, p3);
        *(uint2*)&Psw[l16 * LDPP + ni * 16 + quad * 4] = u;
      }

      // O += P(16x32) x V(32x64); l += P x ones (row-sum on matrix pipe)
      bf16x8v ap = *(const bf16x8v*)&Psw[l16 * LDPP + quad * 8];
      __builtin_amdgcn_s_setprio(1);
      lsum = __builtin_amdgcn_mfma_f32_16x16x32_bf16(ap, vone, lsum, 0, 0, 0);
#pragma unroll
      for (int ni = 0; ni < 4; ++ni) {
        bf16x8v bv = *(const bf16x8v*)
            &Vs[buf][hc * 4096 + (ni * 16 + l16) * 64 +
                     (((hl * 4 + quad) ^ sw) << 3)];
        oacc[ni] = __builtin_amdgcn_mfma_f32_16x16x32_bf16(ap, bv, oacc[ni],
                                                           0, 0, 0);
      }
      __builtin_amdgcn_s_setprio(0);
    }
  };

  // main loop: stage(t+1) at top -> compute(t) -> vmcnt(0)+barrier.
  for (int tt = 0; tt < 16; ++tt) {
    if (tt + 1 < 16) stageKV(tt + 1, (tt + 1) & 1);
    compute(tt & 1);
    if (tt + 1 < 16) {
      asm volatile("s_waitcnt vmcnt(0)" ::: "memory");
      __builtin_amdgcn_s_barrier();
    }
  }

  // epilogue: O / l -> Ctx[b][s][h*64+dh]
  const int b_ = bh >> 4, h_ = bh & 15;
#pragma unroll
  for (int r = 0; r < 4; ++r) {
    int sr = qb * 128 + wave * 16 + quad * 4 + r;
    float inv = 1.0f / fmaxf(lsum[r], 1.0e-20f);
#pragma unroll
    for (int ni = 0; ni < 4; ++ni) {
      int col = h_ * 64 + ni * 16 + l16;
      Ctx[(size_t)(b_ * 2048 + sr) * 1024 + col] =
          __float2bfloat16(fclamp(oacc[ni][r] * inv));
    }
  }
}

extern "C" void kernel_launch(void* const* d_in, const int* in_sizes, int n_in,
                              void* d_out, int out_size, void* d_ws, size_t ws_size,
                              hipStream_t stream) {
  const float* q   = (const float*)d_in[0];
  const float* k   = (const float*)d_in[1];
  const float* v   = (const float*)d_in[2];
  const float* w_q = (const float*)d_in[3];
  const float* b_q = (const float*)d_in[4];
  const float* w_k = (const float*)d_in[5];
  const float* b_k = (const float*)d_in[6];
  const float* w_v = (const float*)d_in[7];
  const float* b_v = (const float*)d_in[8];
  const float* w_o = (const float*)d_in[9];
  const float* b_o = (const float*)d_in[10];
  float* out = (float*)d_out;

  char* ws = (char*)d_ws;
  const size_t MB = (size_t)1024 * 1024;
  bf16* WtQ = (bf16*)(ws + 0 * MB);
  bf16* WtK = (bf16*)(ws + 2 * MB);
  bf16* WtV = (bf16*)(ws + 4 * MB);
  bf16* WtO = (bf16*)(ws + 6 * MB);
  bf16* Qa  = (bf16*)(ws + 8 * MB);   // bf16 activations (8 MiB each)
  bf16* Ka  = (bf16*)(ws + 16 * MB);
  bf16* Va  = (bf16*)(ws + 24 * MB);
  bf16* Qh  = (bf16*)(ws + 32 * MB);  // [2,16,2048,64]
  bf16* Kh  = (bf16*)(ws + 40 * MB);
  bf16* Vt  = (bf16*)(ws + 48 * MB);  // [2,16,64,2048]
  bf16* Ctx = Qa;                     // Qa dead after gemm_qkv

  dim3 tb(256);
  prep<<<dim3(7168), tb, 0, stream>>>(q, k, v, w_q, w_k, w_v, w_o,
                                      Qa, Ka, Va, WtQ, WtK, WtV, WtO);
  gemm_qkv_bf16<<<dim3(32, 8, 3), tb, 0, stream>>>(Qa, Ka, Va, WtQ, WtK, WtV,
                                                   b_q, b_k, b_v, Qh, Kh, Vt);
  attn<<<dim3(512), dim3(512), 0, stream>>>(Qh, Kh, Vt, Ctx);
  gemm_out<<<dim3(32, 16), tb, 0, stream>>>(Ctx, WtO, b_o, out);
}